// Round 10
// baseline (626.687 us; speedup 1.0000x reference)
//
#include <hip/hip_runtime.h>
#include <math.h>

typedef float  f32x4  __attribute__((ext_vector_type(4)));
typedef int    i32x4  __attribute__((ext_vector_type(4)));
typedef int    i32x16 __attribute__((ext_vector_type(16)));

#define H      4096
#define E      64
#define TOPK   8
#define TILE_T 32

// W -> 5 balanced i8 limbs of round(w*2^41), MFMA-B-fragment order (R8-proven):
// Wb[((m*2+e2)*5 + j)*1024 + lane*16 + slot], lane=(h<<5)|(e&31), k=32m+16h+slot
__global__ __launch_bounds__(256)
void prep_w(const float* __restrict__ Wg, signed char* __restrict__ Wb)
{
  int n = blockIdx.x * 256 + threadIdx.x;   // 16384 = e(64) x m(128) x h(2)
  int h = n & 1, m = (n >> 1) & 127, e = n >> 8;
  const float* wp = Wg + e * 4096 + m * 32 + h * 16;
  signed char lb[5][16];
  #pragma unroll
  for (int s = 0; s < 16; ++s) {
    long long v = (long long)rint((double)wp[s] * 2199023255552.0); // 2^41
    #pragma unroll
    for (int j = 0; j < 4; ++j) {
      signed char b = (signed char)(v & 0xff);
      lb[j][s] = b;
      v = (v - b) >> 8;
    }
    lb[4][s] = (signed char)v;
  }
  int lanei = (h << 5) | (e & 31);
  int e2 = e >> 5;
  #pragma unroll
  for (int j = 0; j < 5; ++j) {
    i32x4 d;
    #pragma unroll
    for (int r = 0; r < 4; ++r)
      d[r] = (lb[j][4*r] & 0xFF) | ((lb[j][4*r+1] & 0xFF) << 8)
           | ((lb[j][4*r+2] & 0xFF) << 16) | ((lb[j][4*r+3] & 0xFF) << 24);
    *(i32x4*)(Wb + (((size_t)(m * 2 + e2) * 5 + j) << 10) + lanei * 16) = d;
  }
}

// comp[kQ][e] = C0 * sum_{k in K-quarter} round(w*2^41); exact integer sums.
__global__ __launch_bounds__(64)
void comp_w(const float* __restrict__ Wg, double* __restrict__ compT)
{
  int b = blockIdx.x;            // 256 = kQ(4) x e(64)
  int kQ = b >> 6, e = b & 63;
  int lane = threadIdx.x;
  double s = 0.0;
  #pragma unroll 4
  for (int i = 0; i < 16; ++i)
    s += rint((double)Wg[e * 4096 + kQ * 1024 + i * 64 + lane] * 2199023255552.0);
  #pragma unroll
  for (int off = 32; off >= 1; off >>= 1)
    s += __shfl_xor(s, off);
  if (lane == 0) compT[kQ * 64 + e] = 8421504.0 * s;
}

// Router on the i8 pipe (R8/R9-proven math). R10: 8-wave blocks, waves =
// (K-quarter x expert-half), 32 steps/wave -> 4 waves/SIMD to hide the
// A-gather latency (R9 was 2/SIMD, latency-exposed on every pipe).
__global__ __launch_bounds__(512, 4)
void moe_gate_i8(const float* __restrict__ X, const signed char* __restrict__ Wb,
                 const double* __restrict__ compT, float* __restrict__ out,
                 int n_tokens)
{
  __shared__ double Ls[TILE_T * E];   // 16 KB

  const int tid  = threadIdx.x;
  const int lane = tid & 63;
  const int w    = tid >> 6;     // 0..7
  const int kQ   = w >> 1;       // K quarter 0..3
  const int e2   = w & 1;        // expert half
  const int t0   = blockIdx.x * TILE_T;
  const int l31  = lane & 31;
  const int h    = lane >> 5;

  // ---- probe (lane,reg)->(row,col) readout (R8-proven) ----
  i32x16 z;
  #pragma unroll
  for (int r = 0; r < 16; ++r) z[r] = 0;
  int lab = l31 * 0x01010101;
  i32x4 onev = {0x01010101, 0x01010101, 0x01010101, 0x01010101};
  i32x4 labv = {lab, lab, lab, lab};
  i32x16 pr = __builtin_amdgcn_mfma_i32_32x32x32_i8(labv, onev, z, 0, 0, 0);
  i32x16 pc = __builtin_amdgcn_mfma_i32_32x32x32_i8(onev, labv, z, 0, 0, 0);
  int qrow[16], qcol[16];
  #pragma unroll
  for (int r = 0; r < 16; ++r) { qrow[r] = pr[r] >> 5; qcol[r] = pc[r] >> 5; }

  i32x16 acc3 = z, acc4 = z, acc5 = z, acc6 = z, acc7 = z;

  // lane (h,l31): A-frag = token t0+l31, k = kQ*1024 + m*32 + 16h + slot
  const float* ap = X + (size_t)(t0 + l31) * H + kQ * 1024 + h * 16;
  const signed char* bp = Wb + ((((size_t)(kQ * 32) * 2 + e2) * 5) << 10) + lane * 16;

  f32x4 arA[4], arB[4];          // 2-deep A prefetch (named, static indexing)
  #pragma unroll
  for (int q = 0; q < 4; ++q) {
    arA[q] = *(const f32x4*)(ap + 0 * 32 + 4 * q);
    arB[q] = *(const f32x4*)(ap + 1 * 32 + 4 * q);
  }
  i32x4 bcur[5];
  #pragma unroll
  for (int j = 0; j < 5; ++j)
    bcur[j] = *(const i32x4*)(bp + (j << 10));

  // one 32-k step: convert abuf -> 4 limb planes, prefetch, 14 MFMAs
  #define STEP(abuf, MM)                                                      \
  {                                                                           \
    const int m_ = (MM);                                                      \
    unsigned w32[16];                                                         \
    _Pragma("unroll")                                                         \
    for (int q = 0; q < 4; ++q) {                                             \
      f32x4 xv = abuf[q];                                                     \
      _Pragma("unroll")                                                       \
      for (int jj = 0; jj < 4; ++jj)                                          \
        w32[q*4+jj] = ((unsigned)(int)(xv[jj] * 268435456.0f)) ^ 0x00808080u; \
    }                                                                         \
    if (m_ < 30) {                                                            \
      _Pragma("unroll")                                                       \
      for (int q = 0; q < 4; ++q)                                             \
        abuf[q] = *(const f32x4*)(ap + (m_ + 2) * 32 + 4 * q);                \
    }                                                                         \
    i32x4 bnxt[5];                                                            \
    if (m_ < 31) {                                                            \
      _Pragma("unroll")                                                       \
      for (int j = 0; j < 5; ++j)                                             \
        bnxt[j] = *(const i32x4*)(bp + (size_t)(m_ + 1) * 10240 + (j << 10)); \
    }                                                                         \
    i32x4 a0, a1, a2, a3;                                                     \
    _Pragma("unroll")                                                         \
    for (int r = 0; r < 4; ++r) {                                             \
      unsigned u0 = w32[4*r], u1 = w32[4*r+1], u2 = w32[4*r+2], u3 = w32[4*r+3];\
      unsigned p01, p23;                                                      \
      p01 = __builtin_amdgcn_perm(u1, u0, 0x04000400u);                       \
      p23 = __builtin_amdgcn_perm(u3, u2, 0x04000400u);                       \
      a0[r] = (int)__builtin_amdgcn_perm(p23, p01, 0x05040100u);              \
      p01 = __builtin_amdgcn_perm(u1, u0, 0x05010501u);                       \
      p23 = __builtin_amdgcn_perm(u3, u2, 0x05010501u);                       \
      a1[r] = (int)__builtin_amdgcn_perm(p23, p01, 0x05040100u);              \
      p01 = __builtin_amdgcn_perm(u1, u0, 0x06020602u);                       \
      p23 = __builtin_amdgcn_perm(u3, u2, 0x06020602u);                       \
      a2[r] = (int)__builtin_amdgcn_perm(p23, p01, 0x05040100u);              \
      p01 = __builtin_amdgcn_perm(u1, u0, 0x07030703u);                       \
      p23 = __builtin_amdgcn_perm(u3, u2, 0x07030703u);                       \
      a3[r] = (int)__builtin_amdgcn_perm(p23, p01, 0x05040100u);              \
    }                                                                         \
    acc3 = __builtin_amdgcn_mfma_i32_32x32x32_i8(a0, bcur[3], acc3, 0, 0, 0); \
    acc4 = __builtin_amdgcn_mfma_i32_32x32x32_i8(a0, bcur[4], acc4, 0, 0, 0); \
    acc5 = __builtin_amdgcn_mfma_i32_32x32x32_i8(a1, bcur[4], acc5, 0, 0, 0); \
    acc6 = __builtin_amdgcn_mfma_i32_32x32x32_i8(a2, bcur[4], acc6, 0, 0, 0); \
    acc7 = __builtin_amdgcn_mfma_i32_32x32x32_i8(a3, bcur[4], acc7, 0, 0, 0); \
    acc3 = __builtin_amdgcn_mfma_i32_32x32x32_i8(a1, bcur[2], acc3, 0, 0, 0); \
    acc4 = __builtin_amdgcn_mfma_i32_32x32x32_i8(a1, bcur[3], acc4, 0, 0, 0); \
    acc5 = __builtin_amdgcn_mfma_i32_32x32x32_i8(a2, bcur[3], acc5, 0, 0, 0); \
    acc6 = __builtin_amdgcn_mfma_i32_32x32x32_i8(a3, bcur[3], acc6, 0, 0, 0); \
    acc3 = __builtin_amdgcn_mfma_i32_32x32x32_i8(a2, bcur[1], acc3, 0, 0, 0); \
    acc4 = __builtin_amdgcn_mfma_i32_32x32x32_i8(a2, bcur[2], acc4, 0, 0, 0); \
    acc5 = __builtin_amdgcn_mfma_i32_32x32x32_i8(a3, bcur[2], acc5, 0, 0, 0); \
    acc3 = __builtin_amdgcn_mfma_i32_32x32x32_i8(a3, bcur[0], acc3, 0, 0, 0); \
    acc4 = __builtin_amdgcn_mfma_i32_32x32x32_i8(a3, bcur[1], acc4, 0, 0, 0); \
    if (m_ < 31) {                                                            \
      _Pragma("unroll")                                                       \
      for (int j = 0; j < 5; ++j) bcur[j] = bnxt[j];                          \
    }                                                                         \
  }

  for (int m2 = 0; m2 < 16; ++m2) {
    STEP(arA, 2 * m2);
    STEP(arB, 2 * m2 + 1);
  }
  #undef STEP

  // ---- f64 combine (exact scales; kQ0 writes, kQ1..3 add in turn) ----
  double part[16];
  #pragma unroll
  for (int r = 0; r < 16; ++r) {
    int ex = e2 * 32 + qcol[r];
    part[r] = (16777216.0              * (double)acc3[r]
             + 4294967296.0            * (double)acc4[r]
             + 1099511627776.0         * (double)acc5[r]
             + 281474976710656.0       * (double)acc6[r]
             + 72057594037927936.0     * (double)acc7[r]
             + compT[kQ * 64 + ex]) * 1.6940658945086007e-21;
  }
  if (kQ == 0) {
    #pragma unroll
    for (int r = 0; r < 16; ++r)
      Ls[qrow[r] * E + e2 * 32 + qcol[r]] = part[r];
  }
  __syncthreads();
  #pragma unroll
  for (int g = 1; g < 4; ++g) {
    if (kQ == g) {
      #pragma unroll
      for (int r = 0; r < 16; ++r)
        Ls[qrow[r] * E + e2 * 32 + qcol[r]] += part[r];
    }
    __syncthreads();
  }

  // ---- per-token softmax + top-8 on f64 logits (R2/R4-R9-proven) ----
  for (int tt = 0; tt < 4; tt++) {
    int t = w * 4 + tt;
    double val = Ls[t * E + lane];

    double mx = val;
    #pragma unroll
    for (int off = 32; off >= 1; off >>= 1)
      mx = fmax(mx, __shfl_xor(mx, off));

    double p = exp(val - mx);
    double S = p;
    #pragma unroll
    for (int off = 32; off >= 1; off >>= 1)
      S += __shfl_xor(S, off);

    double cur = val;
    double myw = 0.0; int myidx = 0;
    double psum = 0.0;
    #pragma unroll
    for (int r = 0; r < TOPK; r++) {
      double v = cur; int ii = lane;
      #pragma unroll
      for (int off = 32; off >= 1; off >>= 1) {
        double ov = __shfl_xor(v, off);
        int    oi = __shfl_xor(ii, off);
        if (ov > v || (ov == v && oi < ii)) { v = ov; ii = oi; }
      }
      double pw = __shfl(p, ii);
      psum += pw;
      if (lane == r) { myw = pw; myidx = ii; }
      if (lane == ii) cur = -INFINITY;
    }
    double denom = psum / S + 1e-20;
    if (lane < TOPK) {
      size_t gt = (size_t)(t0 + t);
      out[gt * TOPK + lane] = (float)((myw / S) / denom);
      out[(size_t)n_tokens * TOPK + gt * TOPK + lane] = (float)myidx;
    }
  }
}

extern "C" void kernel_launch(void* const* d_in, const int* in_sizes, int n_in,
                              void* d_out, int out_size, void* d_ws, size_t ws_size,
                              hipStream_t stream)
{
  const float* X  = (const float*)d_in[0];
  const float* Wg = (const float*)d_in[1];
  float* out = (float*)d_out;
  signed char* Wb = (signed char*)d_ws;                 // 1.25 MB limb planes
  double* compT   = (double*)((char*)d_ws + 1310720);   // 2 KB comp table
  int n_tokens = in_sizes[0] / H;                        // 16384

  prep_w<<<64, 256, 0, stream>>>(Wg, Wb);
  comp_w<<<256, 64, 0, stream>>>(Wg, compT);
  moe_gate_i8<<<n_tokens / TILE_T, 512, 0, stream>>>(X, Wb, compT, out, n_tokens);
}

// Round 11
// 196.169 us; speedup vs baseline: 3.1946x; 3.1946x over previous
//
#include <hip/hip_runtime.h>
#include <math.h>

typedef float  f32x4  __attribute__((ext_vector_type(4)));
typedef int    i32x4  __attribute__((ext_vector_type(4)));

#define H      4096
#define E      64
#define TOPK   8
#define TILE_T 16

// W -> 5 balanced i8 limbs of round(w*2^41), B-fragment order for 16x16x64:
// Wb[((m*4+eq)*5 + j)*1024 + lane*16 + slot], lane=(kgrp<<4)|(e&15),
// k = m*64 + kgrp*16 + slot
__global__ __launch_bounds__(256)
void prep_w(const float* __restrict__ Wg, signed char* __restrict__ Wb)
{
  int n = blockIdx.x * 256 + threadIdx.x;   // 16384 = e(64) x m(64) x kgrp(4)
  int kgrp = n & 3, m = (n >> 2) & 63, e = n >> 8;
  const float* wp = Wg + e * 4096 + m * 64 + kgrp * 16;
  signed char lb[5][16];
  #pragma unroll
  for (int s = 0; s < 16; ++s) {
    long long v = (long long)rint((double)wp[s] * 2199023255552.0); // 2^41
    #pragma unroll
    for (int j = 0; j < 4; ++j) {
      signed char b = (signed char)(v & 0xff);
      lb[j][s] = b;
      v = (v - b) >> 8;
    }
    lb[4][s] = (signed char)v;
  }
  int lanei = (kgrp << 4) | (e & 15);
  int eq = e >> 4;
  #pragma unroll
  for (int j = 0; j < 5; ++j) {
    i32x4 d;
    #pragma unroll
    for (int r = 0; r < 4; ++r)
      d[r] = (lb[j][4*r] & 0xFF) | ((lb[j][4*r+1] & 0xFF) << 8)
           | ((lb[j][4*r+2] & 0xFF) << 16) | ((lb[j][4*r+3] & 0xFF) << 24);
    *(i32x4*)(Wb + (((size_t)(m * 4 + eq) * 5 + j) << 10) + lanei * 16) = d;
  }
}

// comp[e] = C0 * sum_k round(w*2^41) over FULL K (no K-split this round).
__global__ __launch_bounds__(64)
void comp_w(const float* __restrict__ Wg, double* __restrict__ compT)
{
  int e = blockIdx.x;            // 64 experts
  int lane = threadIdx.x;
  double s = 0.0;
  #pragma unroll 4
  for (int i = 0; i < 64; ++i)
    s += rint((double)Wg[e * 4096 + i * 64 + lane] * 2199023255552.0);
  #pragma unroll
  for (int off = 32; off >= 1; off >>= 1)
    s += __shfl_xor(s, off);
  if (lane == 0) compT[e] = 8421504.0 * s;
}

// R11: 16x16x64 i8 MFMA (acc = 20 AGPR vs 80) -> fits 4 waves/SIMD at
// <=128 regs. Wave = 16 tok x 16 exp x full K; block = 4 expert-quad waves;
// grid 1024 -> 4 blocks/CU. Pointer-increment addressing (kills the 64-bit
// mul address math R9's VALUBusy exposed). Numerics identical to R8-R10.
__global__ __launch_bounds__(256, 4)
void moe_gate_i8(const float* __restrict__ X, const signed char* __restrict__ Wb,
                 const double* __restrict__ compT, float* __restrict__ out,
                 int n_tokens)
{
  __shared__ double Ls[TILE_T * E];   // 8 KB

  const int tid  = threadIdx.x;
  const int lane = tid & 63;
  const int w    = tid >> 6;     // expert quad 0..3
  const int t0   = blockIdx.x * TILE_T;
  const int l15  = lane & 15;
  const int kg   = lane >> 4;

  // ---- probe (lane,reg)->(row,col) readout of mfma_i32_16x16x64_i8 ----
  i32x4 z = {0, 0, 0, 0};
  int lab = l15 * 0x01010101;
  i32x4 onev = {0x01010101, 0x01010101, 0x01010101, 0x01010101};
  i32x4 labv = {lab, lab, lab, lab};
  i32x4 pr = __builtin_amdgcn_mfma_i32_16x16x64_i8(labv, onev, z, 0, 0, 0);
  i32x4 pc = __builtin_amdgcn_mfma_i32_16x16x64_i8(onev, labv, z, 0, 0, 0);
  int qrow[4], qcol[4];
  #pragma unroll
  for (int r = 0; r < 4; ++r) { qrow[r] = pr[r] >> 6; qcol[r] = pc[r] >> 6; }

  i32x4 acc3 = z, acc4 = z, acc5 = z, acc6 = z, acc7 = z;

  // lane: token t0+l15, k = m*64 + kg*16 + slot
  const float* app = X + (size_t)(t0 + l15) * H + kg * 16;
  const signed char* bpp = Wb + w * 5120 + lane * 16;

  f32x4 ar0 = *(const f32x4*)(app);
  f32x4 ar1 = *(const f32x4*)(app + 4);
  f32x4 ar2 = *(const f32x4*)(app + 8);
  f32x4 ar3 = *(const f32x4*)(app + 12);
  app += 64;

  #pragma unroll 2
  for (int m = 0; m < 64; ++m) {
    // B for this step (L2-resident; issued before the conversion VALU)
    i32x4 b0 = *(const i32x4*)(bpp);
    i32x4 b1 = *(const i32x4*)(bpp + 1024);
    i32x4 b2 = *(const i32x4*)(bpp + 2048);
    i32x4 b3 = *(const i32x4*)(bpp + 3072);
    i32x4 b4 = *(const i32x4*)(bpp + 4096);
    // next-step A (HBM; distance-1 + 4 waves/SIMD hide the rest)
    f32x4 an0, an1, an2, an3;
    if (m < 63) {
      an0 = *(const f32x4*)(app);
      an1 = *(const f32x4*)(app + 4);
      an2 = *(const f32x4*)(app + 8);
      an3 = *(const f32x4*)(app + 12);
    }
    app += 64; bpp += 20480;

    // convert 16 f32 -> biased words (bytes 0..2 ^0x80; C0 comp in compT)
    unsigned w32[16];
    #pragma unroll
    for (int jj = 0; jj < 4; ++jj) {
      w32[0*4+jj] = ((unsigned)(int)(ar0[jj] * 268435456.0f)) ^ 0x00808080u;
      w32[1*4+jj] = ((unsigned)(int)(ar1[jj] * 268435456.0f)) ^ 0x00808080u;
      w32[2*4+jj] = ((unsigned)(int)(ar2[jj] * 268435456.0f)) ^ 0x00808080u;
      w32[3*4+jj] = ((unsigned)(int)(ar3[jj] * 268435456.0f)) ^ 0x00808080u;
    }
    // de-interleave limb bytes (R9-verified perm tree)
    i32x4 a0, a1, a2, a3;
    #pragma unroll
    for (int r = 0; r < 4; ++r) {
      unsigned u0 = w32[4*r], u1 = w32[4*r+1], u2 = w32[4*r+2], u3 = w32[4*r+3];
      unsigned p01, p23;
      p01 = __builtin_amdgcn_perm(u1, u0, 0x04000400u);
      p23 = __builtin_amdgcn_perm(u3, u2, 0x04000400u);
      a0[r] = (int)__builtin_amdgcn_perm(p23, p01, 0x05040100u);
      p01 = __builtin_amdgcn_perm(u1, u0, 0x05010501u);
      p23 = __builtin_amdgcn_perm(u3, u2, 0x05010501u);
      a1[r] = (int)__builtin_amdgcn_perm(p23, p01, 0x05040100u);
      p01 = __builtin_amdgcn_perm(u1, u0, 0x06020602u);
      p23 = __builtin_amdgcn_perm(u3, u2, 0x06020602u);
      a2[r] = (int)__builtin_amdgcn_perm(p23, p01, 0x05040100u);
      p01 = __builtin_amdgcn_perm(u1, u0, 0x07030703u);
      p23 = __builtin_amdgcn_perm(u3, u2, 0x07030703u);
      a3[r] = (int)__builtin_amdgcn_perm(p23, p01, 0x05040100u);
    }
    // 14 limb-pair MFMAs, chain-round-robin (i+j>=3)
    acc3 = __builtin_amdgcn_mfma_i32_16x16x64_i8(a0, b3, acc3, 0, 0, 0);
    acc4 = __builtin_amdgcn_mfma_i32_16x16x64_i8(a0, b4, acc4, 0, 0, 0);
    acc5 = __builtin_amdgcn_mfma_i32_16x16x64_i8(a1, b4, acc5, 0, 0, 0);
    acc6 = __builtin_amdgcn_mfma_i32_16x16x64_i8(a2, b4, acc6, 0, 0, 0);
    acc7 = __builtin_amdgcn_mfma_i32_16x16x64_i8(a3, b4, acc7, 0, 0, 0);
    acc3 = __builtin_amdgcn_mfma_i32_16x16x64_i8(a1, b2, acc3, 0, 0, 0);
    acc4 = __builtin_amdgcn_mfma_i32_16x16x64_i8(a1, b3, acc4, 0, 0, 0);
    acc5 = __builtin_amdgcn_mfma_i32_16x16x64_i8(a2, b3, acc5, 0, 0, 0);
    acc6 = __builtin_amdgcn_mfma_i32_16x16x64_i8(a3, b3, acc6, 0, 0, 0);
    acc3 = __builtin_amdgcn_mfma_i32_16x16x64_i8(a2, b1, acc3, 0, 0, 0);
    acc4 = __builtin_amdgcn_mfma_i32_16x16x64_i8(a2, b2, acc4, 0, 0, 0);
    acc5 = __builtin_amdgcn_mfma_i32_16x16x64_i8(a3, b2, acc5, 0, 0, 0);
    acc3 = __builtin_amdgcn_mfma_i32_16x16x64_i8(a3, b0, acc3, 0, 0, 0);
    acc4 = __builtin_amdgcn_mfma_i32_16x16x64_i8(a3, b1, acc4, 0, 0, 0);

    ar0 = an0; ar1 = an1; ar2 = an2; ar3 = an3;
  }

  // ---- f64 combine: wave owns its 16x16 logits outright ----
  #pragma unroll
  for (int r = 0; r < 4; ++r) {
    int ex = w * 16 + qcol[r];
    double part = (16777216.0              * (double)acc3[r]
                 + 4294967296.0            * (double)acc4[r]
                 + 1099511627776.0         * (double)acc5[r]
                 + 281474976710656.0       * (double)acc6[r]
                 + 72057594037927936.0     * (double)acc7[r]
                 + compT[ex]) * 1.6940658945086007e-21;
    Ls[qrow[r] * E + ex] = part;
  }
  __syncthreads();

  // ---- per-token softmax + top-8: selection on f64 logits (exact),
  // weights in f32 (err ~1e-7 << threshold) ----
  for (int tt = 0; tt < 4; tt++) {
    int t = w * 4 + tt;
    double val = Ls[t * E + lane];

    double mx = val;
    #pragma unroll
    for (int off = 32; off >= 1; off >>= 1)
      mx = fmax(mx, __shfl_xor(mx, off));

    float p = expf((float)(val - mx));
    float S = p;
    #pragma unroll
    for (int off = 32; off >= 1; off >>= 1)
      S += __shfl_xor(S, off);

    double cur = val;
    float myw = 0.f; int myidx = 0;
    float psum = 0.f;
    #pragma unroll
    for (int r = 0; r < TOPK; r++) {
      double v = cur; int ii = lane;
      #pragma unroll
      for (int off = 32; off >= 1; off >>= 1) {
        double ov = __shfl_xor(v, off);
        int    oi = __shfl_xor(ii, off);
        if (ov > v || (ov == v && oi < ii)) { v = ov; ii = oi; }
      }
      float pw = __shfl(p, ii);
      psum += pw;
      if (lane == r) { myw = pw; myidx = ii; }
      if (lane == ii) cur = -INFINITY;
    }
    float denom = psum + 1e-20f * S;
    if (lane < TOPK) {
      size_t gt = (size_t)(t0 + t);
      out[gt * TOPK + lane] = myw / denom;
      out[(size_t)n_tokens * TOPK + gt * TOPK + lane] = (float)myidx;
    }
  }
}

extern "C" void kernel_launch(void* const* d_in, const int* in_sizes, int n_in,
                              void* d_out, int out_size, void* d_ws, size_t ws_size,
                              hipStream_t stream)
{
  const float* X  = (const float*)d_in[0];
  const float* Wg = (const float*)d_in[1];
  float* out = (float*)d_out;
  signed char* Wb = (signed char*)d_ws;                 // 1.25 MB limb planes
  double* compT   = (double*)((char*)d_ws + 1310720);   // 512 B comp table
  int n_tokens = in_sizes[0] / H;                        // 16384

  prep_w<<<64, 256, 0, stream>>>(Wg, Wb);
  comp_w<<<64, 64, 0, stream>>>(Wg, compT);
  moe_gate_i8<<<n_tokens / TILE_T, 256, 0, stream>>>(X, Wb, compT, out, n_tokens);
}

// Round 13
// 132.727 us; speedup vs baseline: 4.7216x; 1.4780x over previous
//
#include <hip/hip_runtime.h>
#include <math.h>

typedef float  f32x4  __attribute__((ext_vector_type(4)));
typedef int    i32x4  __attribute__((ext_vector_type(4)));

#define H      4096
#define E      64
#define TOPK   8
#define TILE_T 16
#define CK     512     // k per staged chunk
#define MS     8       // 64-k MFMA steps per chunk
#define NCH    8       // chunks

// W -> 5 balanced i8 limbs of round(w*2^41), B-fragment order for 16x16x64
// (R11-proven): Wb[((m*4+eq)*5+j)*1024 + lane*16 + slot], lane=(kgrp<<4)|(e&15)
__global__ __launch_bounds__(256)
void prep_w(const float* __restrict__ Wg, signed char* __restrict__ Wb)
{
  int n = blockIdx.x * 256 + threadIdx.x;   // 16384 = e(64) x m(64) x kgrp(4)
  int kgrp = n & 3, m = (n >> 2) & 63, e = n >> 8;
  const float* wp = Wg + e * 4096 + m * 64 + kgrp * 16;
  signed char lb[5][16];
  #pragma unroll
  for (int s = 0; s < 16; ++s) {
    long long v = (long long)rint((double)wp[s] * 2199023255552.0); // 2^41
    #pragma unroll
    for (int j = 0; j < 4; ++j) {
      signed char b = (signed char)(v & 0xff);
      lb[j][s] = b;
      v = (v - b) >> 8;
    }
    lb[4][s] = (signed char)v;
  }
  int lanei = (kgrp << 4) | (e & 15);
  int eq = e >> 4;
  #pragma unroll
  for (int j = 0; j < 5; ++j) {
    i32x4 d;
    #pragma unroll
    for (int r = 0; r < 4; ++r)
      d[r] = (lb[j][4*r] & 0xFF) | ((lb[j][4*r+1] & 0xFF) << 8)
           | ((lb[j][4*r+2] & 0xFF) << 16) | ((lb[j][4*r+3] & 0xFF) << 24);
    *(i32x4*)(Wb + (((size_t)(m * 4 + eq) * 5 + j) << 10) + lanei * 16) = d;
  }
}

// comp[e] = C0 * sum_k round(w*2^41), full K (R11-proven).
__global__ __launch_bounds__(64)
void comp_w(const float* __restrict__ Wg, double* __restrict__ compT)
{
  int e = blockIdx.x;
  int lane = threadIdx.x;
  double s = 0.0;
  #pragma unroll 4
  for (int i = 0; i < 64; ++i)
    s += rint((double)Wg[e * 4096 + i * 64 + lane] * 2199023255552.0);
  #pragma unroll
  for (int off = 32; off >= 1; off >>= 1)
    s += __shfl_xor(s, off);
  if (lane == 0) compT[e] = 8421504.0 * s;
}

// R13 = R12 with the swizzle made BIJECTIVE (rule #21): XOR applied to the
// tok nibble itself, addr = kgrp*1024 + j*256 + ((tok*16) ^ ((kgrp>>1)&7)<<4).
// R12's "base + (0x100 ^ swz)" was an ADD against tok*16 -> carries -> write
// collisions -> scrambled logits. Same formula on write and read.
__global__ __launch_bounds__(256, 4)
void moe_gate_i8(const float* __restrict__ X, const signed char* __restrict__ Wb,
                 const double* __restrict__ compT, float* __restrict__ out,
                 int n_tokens)
{
  __shared__ char  As[32768];        // [kgrp 32][limb 4][tok 16] x 16B, swizzled
  __shared__ double Ls[TILE_T * E];  // 8 KB logits

  const int tid  = threadIdx.x;
  const int lane = tid & 63;
  const int w    = tid >> 6;     // expert quad 0..3
  const int t0   = blockIdx.x * TILE_T;
  const int l15  = lane & 15;
  const int kg   = lane >> 4;

  // ---- probe (lane,reg)->(row,col) readout (R11-proven) ----
  i32x4 z = {0, 0, 0, 0};
  int lab = l15 * 0x01010101;
  i32x4 onev = {0x01010101, 0x01010101, 0x01010101, 0x01010101};
  i32x4 labv = {lab, lab, lab, lab};
  i32x4 pr = __builtin_amdgcn_mfma_i32_16x16x64_i8(labv, onev, z, 0, 0, 0);
  i32x4 pc = __builtin_amdgcn_mfma_i32_16x16x64_i8(onev, labv, z, 0, 0, 0);
  int qrow[4], qcol[4];
  #pragma unroll
  for (int r = 0; r < 4; ++r) { qrow[r] = pr[r] >> 6; qcol[r] = pc[r] >> 6; }

  i32x4 acc3 = z, acc4 = z, acc5 = z, acc6 = z, acc7 = z;

  // staging mapping: thread = (token tt, 32-float segment ks)
  const int tt = tid >> 4;
  const int ks = tid & 15;
  const float* xp = X + (size_t)(t0 + tt) * H + ks * 32;

  const signed char* bpp = Wb + w * 5120 + lane * 16;

  f32x4 xr[8];
  #pragma unroll
  for (int q = 0; q < 8; ++q) xr[q] = *(const f32x4*)(xp + 4 * q);
  xp += CK;

  for (int c = 0; c < NCH; ++c) {
    // ---- convert 32 floats -> limb words, write LDS (once per block) ----
    #pragma unroll
    for (int hf = 0; hf < 2; ++hf) {
      unsigned w32[16];
      #pragma unroll
      for (int r = 0; r < 4; ++r) {
        f32x4 xv = xr[hf * 4 + r];
        #pragma unroll
        for (int jj = 0; jj < 4; ++jj)
          w32[r*4+jj] = ((unsigned)(int)(xv[jj] * 268435456.0f)) ^ 0x00808080u;
      }
      i32x4 W0, W1, W2, W3;   // per-limb words, elem r = float-group r
      #pragma unroll
      for (int r = 0; r < 4; ++r) {
        unsigned u0 = w32[4*r], u1 = w32[4*r+1], u2 = w32[4*r+2], u3 = w32[4*r+3];
        unsigned p01, p23;
        p01 = __builtin_amdgcn_perm(u1, u0, 0x04000400u);
        p23 = __builtin_amdgcn_perm(u3, u2, 0x04000400u);
        W0[r] = (int)__builtin_amdgcn_perm(p23, p01, 0x05040100u);
        p01 = __builtin_amdgcn_perm(u1, u0, 0x05010501u);
        p23 = __builtin_amdgcn_perm(u3, u2, 0x05010501u);
        W1[r] = (int)__builtin_amdgcn_perm(p23, p01, 0x05040100u);
        p01 = __builtin_amdgcn_perm(u1, u0, 0x06020602u);
        p23 = __builtin_amdgcn_perm(u3, u2, 0x06020602u);
        W2[r] = (int)__builtin_amdgcn_perm(p23, p01, 0x05040100u);
        p01 = __builtin_amdgcn_perm(u1, u0, 0x07030703u);
        p23 = __builtin_amdgcn_perm(u3, u2, 0x07030703u);
        W3[r] = (int)__builtin_amdgcn_perm(p23, p01, 0x05040100u);
      }
      // bijective swizzle: XOR on the tok nibble (carry-free)
      const int kgrp = ks * 2 + hf;
      const int swzw = (ks & 7) << 4;               // = ((kgrp>>1)&7)<<4
      char* base = As + (kgrp << 10) + (((tt << 4) ^ swzw));
      *(i32x4*)(base + 0x000) = W0;
      *(i32x4*)(base + 0x100) = W1;
      *(i32x4*)(base + 0x200) = W2;
      *(i32x4*)(base + 0x300) = W3;
    }
    __syncthreads();

    // prefetch next chunk (VMEM in flight under the consume phase)
    if (c < NCH - 1) {
      #pragma unroll
      for (int q = 0; q < 8; ++q) xr[q] = *(const f32x4*)(xp + 4 * q);
      xp += CK;
    }

    // ---- consume: MS steps x {4 ds_read + 5 B loads + 14 MFMAs} ----
    #pragma unroll
    for (int m = 0; m < MS; ++m) {
      const int kq   = 4 * m + kg;
      const int swzr = ((kq >> 1) & 7) << 4;
      const char* abase = As + (kq << 10) + (((l15 << 4) ^ swzr));
      i32x4 a0 = *(const i32x4*)(abase + 0x000);
      i32x4 a1 = *(const i32x4*)(abase + 0x100);
      i32x4 a2 = *(const i32x4*)(abase + 0x200);
      i32x4 a3 = *(const i32x4*)(abase + 0x300);
      i32x4 b0 = *(const i32x4*)(bpp);
      i32x4 b1 = *(const i32x4*)(bpp + 1024);
      i32x4 b2 = *(const i32x4*)(bpp + 2048);
      i32x4 b3 = *(const i32x4*)(bpp + 3072);
      i32x4 b4 = *(const i32x4*)(bpp + 4096);
      bpp += 20480;
      acc3 = __builtin_amdgcn_mfma_i32_16x16x64_i8(a0, b3, acc3, 0, 0, 0);
      acc4 = __builtin_amdgcn_mfma_i32_16x16x64_i8(a0, b4, acc4, 0, 0, 0);
      acc5 = __builtin_amdgcn_mfma_i32_16x16x64_i8(a1, b4, acc5, 0, 0, 0);
      acc6 = __builtin_amdgcn_mfma_i32_16x16x64_i8(a2, b4, acc6, 0, 0, 0);
      acc7 = __builtin_amdgcn_mfma_i32_16x16x64_i8(a3, b4, acc7, 0, 0, 0);
      acc3 = __builtin_amdgcn_mfma_i32_16x16x64_i8(a1, b2, acc3, 0, 0, 0);
      acc4 = __builtin_amdgcn_mfma_i32_16x16x64_i8(a1, b3, acc4, 0, 0, 0);
      acc5 = __builtin_amdgcn_mfma_i32_16x16x64_i8(a2, b3, acc5, 0, 0, 0);
      acc6 = __builtin_amdgcn_mfma_i32_16x16x64_i8(a3, b3, acc6, 0, 0, 0);
      acc3 = __builtin_amdgcn_mfma_i32_16x16x64_i8(a2, b1, acc3, 0, 0, 0);
      acc4 = __builtin_amdgcn_mfma_i32_16x16x64_i8(a2, b2, acc4, 0, 0, 0);
      acc5 = __builtin_amdgcn_mfma_i32_16x16x64_i8(a3, b2, acc5, 0, 0, 0);
      acc3 = __builtin_amdgcn_mfma_i32_16x16x64_i8(a3, b0, acc3, 0, 0, 0);
      acc4 = __builtin_amdgcn_mfma_i32_16x16x64_i8(a3, b1, acc4, 0, 0, 0);
    }
    __syncthreads();
  }

  // ---- f64 combine: wave owns its 16x16 logits (R11-proven) ----
  #pragma unroll
  for (int r = 0; r < 4; ++r) {
    int ex = w * 16 + qcol[r];
    double part = (16777216.0              * (double)acc3[r]
                 + 4294967296.0            * (double)acc4[r]
                 + 1099511627776.0         * (double)acc5[r]
                 + 281474976710656.0       * (double)acc6[r]
                 + 72057594037927936.0     * (double)acc7[r]
                 + compT[ex]) * 1.6940658945086007e-21;
    Ls[qrow[r] * E + ex] = part;
  }
  __syncthreads();

  // ---- softmax + top-8: selection on f64 logits, weights in f32 ----
  for (int tt2 = 0; tt2 < 4; tt2++) {
    int t = w * 4 + tt2;
    double val = Ls[t * E + lane];

    double mx = val;
    #pragma unroll
    for (int off = 32; off >= 1; off >>= 1)
      mx = fmax(mx, __shfl_xor(mx, off));

    float p = expf((float)(val - mx));
    float S = p;
    #pragma unroll
    for (int off = 32; off >= 1; off >>= 1)
      S += __shfl_xor(S, off);

    double cur = val;
    float myw = 0.f; int myidx = 0;
    float psum = 0.f;
    #pragma unroll
    for (int r = 0; r < TOPK; r++) {
      double v = cur; int ii = lane;
      #pragma unroll
      for (int off = 32; off >= 1; off >>= 1) {
        double ov = __shfl_xor(v, off);
        int    oi = __shfl_xor(ii, off);
        if (ov > v || (ov == v && oi < ii)) { v = ov; ii = oi; }
      }
      float pw = __shfl(p, ii);
      psum += pw;
      if (lane == r) { myw = pw; myidx = ii; }
      if (lane == ii) cur = -INFINITY;
    }
    float denom = psum + 1e-20f * S;
    if (lane < TOPK) {
      size_t gt = (size_t)(t0 + t);
      out[gt * TOPK + lane] = myw / denom;
      out[(size_t)n_tokens * TOPK + gt * TOPK + lane] = (float)myidx;
    }
  }
}

extern "C" void kernel_launch(void* const* d_in, const int* in_sizes, int n_in,
                              void* d_out, int out_size, void* d_ws, size_t ws_size,
                              hipStream_t stream)
{
  const float* X  = (const float*)d_in[0];
  const float* Wg = (const float*)d_in[1];
  float* out = (float*)d_out;
  signed char* Wb = (signed char*)d_ws;                 // 1.25 MB limb planes
  double* compT   = (double*)((char*)d_ws + 1310720);   // 512 B comp table
  int n_tokens = in_sizes[0] / H;                        // 16384

  prep_w<<<64, 256, 0, stream>>>(Wg, Wb);
  comp_w<<<64, 64, 0, stream>>>(Wg, compT);
  moe_gate_i8<<<n_tokens / TILE_T, 256, 0, stream>>>(X, Wb, compT, out, n_tokens);
}